// Round 4
// baseline (259.250 us; speedup 1.0000x reference)
//
#include <hip/hip_runtime.h>

// Problem dims
#define B_SZ 32
#define L_SZ 256
#define D_SZ 512
#define F_SZ 2048
#define E_SZ 8
#define P_SZ 64   // B_SZ * TOP_K
#define BK2  32   // LDS sub-tile K width

typedef __attribute__((ext_vector_type(8)))  short bf16x8;
typedef __attribute__((ext_vector_type(16))) float f32x16;

// f32 -> bf16 round-to-nearest-even (finite inputs only)
__device__ __forceinline__ unsigned short f2bf(float f) {
  unsigned int u = __builtin_bit_cast(unsigned int, f);
  u += 0x7fffu + ((u >> 16) & 1u);
  return (unsigned short)(u >> 16);
}

// async global->LDS, 16B per lane; LDS dest is wave-uniform base + lane*16
__device__ __forceinline__ void async16(const void* g, void* l) {
  __builtin_amdgcn_global_load_lds(
      (const __attribute__((address_space(1))) unsigned int*)g,
      (__attribute__((address_space(3))) unsigned int*)l, 16, 0, 0);
}

// exact gelu via A&S 7.1.26 erf (max abs err ~1.5e-7), fast hw exp/rcp
__device__ __forceinline__ float gelu_f(float x) {
  float a = fabsf(x) * 0.70710678118654752f;
  float t = __builtin_amdgcn_rcpf(1.0f + 0.3275911f * a);
  float y = t * (0.254829592f +
            t * (-0.284496736f +
            t * (1.421413741f +
            t * (-1.453152027f +
            t * 1.061405429f))));
  float e = __expf(-a * a);
  float erf_abs = 1.0f - y * e;
  float erf_v = (x < 0.f) ? -erf_abs : erf_abs;
  return 0.5f * x * (1.0f + erf_v);
}

// LDS-tile transpose+convert helper, templated on block size NT (256/512):
// in [z-block pre-offset] [R][C] f32 -> out [C][R] bf16, 64x64 tile at
// (r0, c0). tile = float[64][65] in LDS.
template <int NT>
__device__ __forceinline__ void transpose_tile(
    const float* __restrict__ ip, unsigned short* __restrict__ op,
    int R, int C, int r0, int c0, float* tile, int tid) {
  int tx = tid & 63, ty = tid >> 6;
  constexpr int RY = NT / 64;   // rows per load pass
#pragma unroll
  for (int i = 0; i < 64 / RY; ++i) {
    int r = i * RY + ty;
    tile[r * 65 + tx] = ip[(size_t)(r0 + r) * C + c0 + tx];
  }
  __syncthreads();
#pragma unroll
  for (int uu = 0; uu < 1024 / NT; ++uu) {
    int u = uu * NT + tid;
    int cc = u >> 4, q = u & 15;
    ushort4 o;
    o.x = f2bf(tile[(q * 4 + 0) * 65 + cc]);
    o.y = f2bf(tile[(q * 4 + 1) * 65 + cc]);
    o.z = f2bf(tile[(q * 4 + 2) * 65 + cc]);
    o.w = f2bf(tile[(q * 4 + 3) * 65 + cc]);
    *(ushort4*)(op + (size_t)(c0 + cc) * R + r0 + q * 4) = o;
  }
}

// ------------- prep: gates | x->bf16 | W1^T->bf16 ----------------------
#define PREP_CONV_BLKS 4096
#define PREP_TR_BLKS   2048
#define PREP_TOTAL     (1 + PREP_CONV_BLKS + PREP_TR_BLKS)

__global__ __launch_bounds__(256) void prep_kernel(
    const float* __restrict__ logits, const int* __restrict__ masks,
    const float* __restrict__ x,
    const float* __restrict__ W1,
    int* __restrict__ sel_e, float* __restrict__ sel_g,
    unsigned short* __restrict__ xb,
    unsigned short* __restrict__ w1t) {
  __shared__ float tile[64 * 65];
  int blk = blockIdx.x;
  int tid = threadIdx.x;

  if (blk == 0) {
    int b = tid;
    if (b >= B_SZ) return;
    float lg[E_SZ], p[E_SZ];
    float mx = -1e30f;
    for (int e = 0; e < E_SZ; ++e) { lg[e] = logits[b * E_SZ + e]; mx = fmaxf(mx, lg[e]); }
    float s = 0.f;
    for (int e = 0; e < E_SZ; ++e) { p[e] = expf(lg[e] - mx); s += p[e]; }
    for (int e = 0; e < E_SZ; ++e) p[e] = (masks[b * E_SZ + e] == 1) ? (p[e] / s) : 0.f;
    int i0 = 0, i1 = 1; float v0 = -1.f, v1 = -1.f;
    for (int e = 0; e < E_SZ; ++e) {
      float v = p[e];
      if (v > v0)      { v1 = v0; i1 = i0; v0 = v; i0 = e; }
      else if (v > v1) { v1 = v;  i1 = e; }
    }
    float den = v0 + v1 + 1e-9f;
    sel_e[2 * b] = i0;  sel_e[2 * b + 1] = i1;
    sel_g[2 * b] = v0 / den;
    sel_g[2 * b + 1] = v1 / den;
    return;
  }
  blk -= 1;

  if (blk < PREP_CONV_BLKS) {
    int i = blk * 256 + tid;
    float4 v = ((const float4*)x)[i];
    ushort4 o;
    o.x = f2bf(v.x); o.y = f2bf(v.y); o.z = f2bf(v.z); o.w = f2bf(v.w);
    ((ushort4*)xb)[i] = o;
    return;
  }
  blk -= PREP_CONV_BLKS;

  // W1 [E][D][F] -> w1t [E][F][D] : R=D=512, C=F=2048, 8x32 tiles (ls=5)
  int z = blk >> 8;
  int rem = blk & 255;
  int tr = rem >> 5, tc = rem & 31;
  transpose_tile<256>(W1 + (size_t)z * D_SZ * F_SZ, w1t + (size_t)z * D_SZ * F_SZ,
                      D_SZ, F_SZ, tr * 64, tc * 64, tile, tid);
}

// ------------- stage 1 + backfilled W2 transpose -----------------------
// blocks [0,1024): H[p] = gelu(X_b @ W1[e] + b1[e]) — 512 threads, block
//   tile 128(L)x256(F), 8 waves (2M x 4N) each owning 64x64. BK=32
//   ping-pong, T3-minimum order (stage t+1 -> compute t -> one barrier).
//   [measured r2/r3: 67.5 µs, MfmaUtil 21% — frozen]
// blocks [1024,3072): W2 [E][F][D] -> w2t [E][D][F] transpose backfill.
__global__ __launch_bounds__(512, 4) void moe_gemm1(
    const unsigned short* __restrict__ Xb,
    const unsigned short* __restrict__ W1t,
    const float* __restrict__ b1,
    const int* __restrict__ sel_e,
    unsigned short* __restrict__ H,
    const float* __restrict__ W2,
    unsigned short* __restrict__ w2t) {
  __shared__ __align__(16) char smem[49152];   // As 2x8KB | Bs 2x16KB
  int tid = threadIdx.x;
  int lin = blockIdx.x;

  if (lin >= 1024) {
    // W2 transpose role: R=F=2048, C=D=512, 32x8 tiles (ls=3)
    int blk = lin - 1024;
    int z = blk >> 8;
    int rem = blk & 255;
    int tr = rem >> 3, tc = rem & 7;
    transpose_tile<512>(W2 + (size_t)z * F_SZ * D_SZ, w2t + (size_t)z * F_SZ * D_SZ,
                        F_SZ, D_SZ, tr * 64, tc * 64, (float*)smem, tid);
    return;
  }

  unsigned short* As = (unsigned short*)smem;            // [2][128*32]
  unsigned short* Bs = (unsigned short*)(smem + 16384);  // [2][256*32]

  int f  = lin & 7;
  int l0 = ((lin >> 3) & 1) * 128;
  int p  = lin >> 4;
  int f0 = f * 256;
  int b  = p >> 1;
  int e  = sel_e[p];

  int lane = tid & 63;
  int w = tid >> 6;          // 0..7
  int wm = w & 1, wn = w >> 1;   // 2 x 4 wave grid over 128x256
  int m32 = lane & 31, kh = lane >> 5;
  int sw = (m32 >> 1) & 3;       // read-side XOR swizzle

  const unsigned short* Abase = Xb  + ((size_t)b * L_SZ + l0) * D_SZ;
  const unsigned short* Bbase = W1t + ((size_t)e * F_SZ + f0) * D_SZ;

  // staging: A = 512 segs of 16B (1/thread), B = 1024 segs (2/thread).
  // seg (row, slot) fetches global k-chunk slot ^ ((row>>1)&3).
  int sa   = tid;
  int rowa = sa >> 2,  ka  = ((sa  & 3) ^ ((rowa >> 1) & 3)) * 8;
  int sb1  = tid + 512;
  int rowb = sb1 >> 2, kb1 = ((sb1 & 3) ^ ((rowb >> 1) & 3)) * 8;

  const size_t aoffA  = (size_t)rowa * D_SZ + ka;    // A rows 0..127 (also B rows 0..127)
  const size_t aoffB1 = (size_t)rowb * D_SZ + kb1;   // B rows 128..255

  f32x16 acc[2][2] = {};

#define G1_COMPUTE(CB)                                                       \
  _Pragma("unroll")                                                          \
  for (int s = 0; s < 2; ++s) {                                              \
    int ko = ((((s << 1) | kh) ^ sw) << 3);                                  \
    bf16x8 a0  = *(const bf16x8*)&As[(CB) * 4096 + (wm * 64 +      m32) * BK2 + ko]; \
    bf16x8 a1  = *(const bf16x8*)&As[(CB) * 4096 + (wm * 64 + 32 + m32) * BK2 + ko]; \
    bf16x8 b0  = *(const bf16x8*)&Bs[(CB) * 8192 + (wn * 64 +      m32) * BK2 + ko]; \
    bf16x8 b1f = *(const bf16x8*)&Bs[(CB) * 8192 + (wn * 64 + 32 + m32) * BK2 + ko]; \
    acc[0][0] = __builtin_amdgcn_mfma_f32_32x32x16_bf16(a0, b0,  acc[0][0], 0, 0, 0); \
    acc[0][1] = __builtin_amdgcn_mfma_f32_32x32x16_bf16(a0, b1f, acc[0][1], 0, 0, 0); \
    acc[1][0] = __builtin_amdgcn_mfma_f32_32x32x16_bf16(a1, b0,  acc[1][0], 0, 0, 0); \
    acc[1][1] = __builtin_amdgcn_mfma_f32_32x32x16_bf16(a1, b1f, acc[1][1], 0, 0, 0); \
  }

  // prologue: stage sub-tile 0 into buf 0
  async16(Abase + aoffA,  &As[sa * 8]);
  async16(Bbase + aoffA,  &Bs[sa * 8]);
  async16(Bbase + aoffB1, &Bs[sb1 * 8]);
  __syncthreads();

#pragma unroll 2
  for (int t = 0; t < 15; ++t) {
    int cb = t & 1, nb = cb ^ 1;
    int kk = (t + 1) * BK2;
    async16(Abase + aoffA  + kk, &As[nb * 4096 + sa * 8]);
    async16(Bbase + aoffA  + kk, &Bs[nb * 8192 + sa * 8]);
    async16(Bbase + aoffB1 + kk, &Bs[nb * 8192 + sb1 * 8]);
    G1_COMPUTE(cb)
    __syncthreads();
  }
  G1_COMPUTE(1)
#undef G1_COMPUTE

  // epilogue: +b1, gelu, bf16 direct stores (32 lanes -> 64B contiguous)
  float b1v[2];
#pragma unroll
  for (int tj = 0; tj < 2; ++tj)
    b1v[tj] = b1[e * F_SZ + f0 + wn * 64 + tj * 32 + m32];

  unsigned short* Hp = H + ((size_t)p * L_SZ + l0) * F_SZ + f0;
#pragma unroll
  for (int ti = 0; ti < 2; ++ti)
#pragma unroll
    for (int tj = 0; tj < 2; ++tj) {
      int col = wn * 64 + tj * 32 + m32;
#pragma unroll
      for (int r = 0; r < 16; ++r) {
        int row = wm * 64 + ti * 32 + (r & 3) + 8 * (r >> 2) + 4 * kh;
        Hp[(size_t)row * F_SZ + col] = f2bf(gelu_f(acc[ti][tj][r] + b1v[tj]));
      }
    }
}

// ------------- stage 2 (slot-split, full K, no atomics) ----------------
// even slot p -> part = g0*acc ; odd slot p -> Out = g1*acc + gate-wtd b2
// 128(L)x64(D) tiles, 128-thread/2-wave blocks, grid 1024 -> 4 blocks/CU
// (r3's occupancy win, kept). Round-4 change: BK=32 ping-pong with the
// T3-minimum order — issue the 6 loads for sub-tile t+1 into the other
// buffer, compute sub-tile t, then ONE __syncthreads. r3 had
// stage->sync->compute->sync: the drain sat right after the load issue,
// exposing full L2/L3 latency every step (MfmaUtil 20%, VALUBusy 7%).
__global__ __launch_bounds__(128, 2) void moe_gemm2(
    const unsigned short* __restrict__ H,
    const unsigned short* __restrict__ W2t,
    const float* __restrict__ b2,
    const int* __restrict__ sel_e,
    const float* __restrict__ sel_g,
    float* __restrict__ part,
    float* __restrict__ Out) {
  __shared__ __align__(16) unsigned short As[2][128 * BK2];  // 16 KB
  __shared__ __align__(16) unsigned short Bs[2][64 * BK2];   //  8 KB

  int lin = blockIdx.x;
  int q   = lin & 7;             // XCD
  int d   = (lin >> 3) & 7;      // 8 d-tiles of 64 — same XCD across d
  int g8  = lin >> 6;
  int gg  = g8 * 8 + q;          // (p, l-tile), 0..127
  int p   = gg >> 1;
  int l0  = (gg & 1) * 128;
  int d0  = d * 64;
  int b   = p >> 1;
  int e   = sel_e[p];
  float g = sel_g[p];

  int tid = threadIdx.x;         // 0..127
  int lane = tid & 63;
  int wm = tid >> 6;             // 2 waves = M split; wn == 0
  int m32 = lane & 31, kh = lane >> 5;
  int sw = (m32 >> 1) & 3;

  const unsigned short* Abase = H   + ((size_t)p * L_SZ + l0) * F_SZ;
  const unsigned short* Bbase = W2t + ((size_t)e * D_SZ + d0) * F_SZ;

  // staging: A = 512 segs of 16B (4/thread), B = 256 segs (2/thread).
  // seg (row, slot) fetches global k-chunk slot ^ ((row>>1)&3).
  int    saA[4]; size_t aoffA[4];
#pragma unroll
  for (int j = 0; j < 4; ++j) {
    int s = tid + j * 128;
    int row = s >> 2, ks = ((s & 3) ^ ((row >> 1) & 3)) * 8;
    saA[j] = s; aoffA[j] = (size_t)row * F_SZ + ks;
  }
  int    saB[2]; size_t aoffB[2];
#pragma unroll
  for (int j = 0; j < 2; ++j) {
    int s = tid + j * 128;
    int row = s >> 2, ks = ((s & 3) ^ ((row >> 1) & 3)) * 8;
    saB[j] = s; aoffB[j] = (size_t)row * F_SZ + ks;
  }

  f32x16 acc[2][2] = {};

#define G2_COMPUTE(CB)                                                       \
  _Pragma("unroll")                                                          \
  for (int s = 0; s < 2; ++s) {     /* K=16 substep */                       \
    int ko = (((s << 1) | kh) ^ sw) << 3;                                    \
    bf16x8 a0  = *(const bf16x8*)&As[CB][(wm * 64 +      m32) * BK2 + ko];   \
    bf16x8 a1  = *(const bf16x8*)&As[CB][(wm * 64 + 32 + m32) * BK2 + ko];   \
    bf16x8 b0  = *(const bf16x8*)&Bs[CB][(          m32) * BK2 + ko];        \
    bf16x8 b1f = *(const bf16x8*)&Bs[CB][(     32 + m32) * BK2 + ko];        \
    acc[0][0] = __builtin_amdgcn_mfma_f32_32x32x16_bf16(a0, b0,  acc[0][0], 0, 0, 0); \
    acc[0][1] = __builtin_amdgcn_mfma_f32_32x32x16_bf16(a0, b1f, acc[0][1], 0, 0, 0); \
    acc[1][0] = __builtin_amdgcn_mfma_f32_32x32x16_bf16(a1, b0,  acc[1][0], 0, 0, 0); \
    acc[1][1] = __builtin_amdgcn_mfma_f32_32x32x16_bf16(a1, b1f, acc[1][1], 0, 0, 0); \
  }

  // prologue: stage sub-tile 0 into buf 0
#pragma unroll
  for (int j = 0; j < 4; ++j) async16(Abase + aoffA[j], &As[0][saA[j] * 8]);
#pragma unroll
  for (int j = 0; j < 2; ++j) async16(Bbase + aoffB[j], &Bs[0][saB[j] * 8]);
  __syncthreads();

#pragma unroll 2
  for (int t = 0; t < 63; ++t) {      // K = 2048 = 64 sub-tiles of 32
    int cb = t & 1, nb = cb ^ 1;
    int kk = (t + 1) * BK2;
#pragma unroll
    for (int j = 0; j < 4; ++j)
      async16(Abase + aoffA[j] + kk, &As[nb][saA[j] * 8]);
#pragma unroll
    for (int j = 0; j < 2; ++j)
      async16(Bbase + aoffB[j] + kk, &Bs[nb][saB[j] * 8]);
    G2_COMPUTE(cb)
    __syncthreads();
  }
  G2_COMPUTE(1)
#undef G2_COMPUTE

  // epilogue: gate-scale (+ gate-weighted b2 on odd slot), direct f32 stores
  float bias[2] = {0.f, 0.f};
  if (p & 1) {
    int e0 = sel_e[2 * b], e1 = sel_e[2 * b + 1];
    float g0 = sel_g[2 * b], g1 = sel_g[2 * b + 1];
#pragma unroll
    for (int tj = 0; tj < 2; ++tj) {
      int dd = d0 + tj * 32 + m32;
      bias[tj] = g0 * b2[e0 * D_SZ + dd] + g1 * b2[e1 * D_SZ + dd];
    }
  }
  float* dst = (p & 1) ? Out : part;
  float* Op = dst + ((size_t)b * L_SZ + l0) * D_SZ + d0;
#pragma unroll
  for (int ti = 0; ti < 2; ++ti)
#pragma unroll
    for (int tj = 0; tj < 2; ++tj) {
      int col = tj * 32 + m32;
#pragma unroll
      for (int r = 0; r < 16; ++r) {
        int row = wm * 64 + ti * 32 + (r & 3) + 8 * (r >> 2) + 4 * kh;
        Op[(size_t)row * D_SZ + col] = g * acc[ti][tj][r] + bias[tj];
      }
    }
}

// ------------- combine: Out += part ------------------------------------
__global__ __launch_bounds__(256) void combine_kernel(
    const float* __restrict__ part, float* __restrict__ Out) {
  int i = blockIdx.x * 256 + threadIdx.x;
  float4 pv = ((const float4*)part)[i];
  float4 o  = ((float4*)Out)[i];
  o.x += pv.x; o.y += pv.y; o.z += pv.z; o.w += pv.w;
  ((float4*)Out)[i] = o;
}

extern "C" void kernel_launch(void* const* d_in, const int* in_sizes, int n_in,
                              void* d_out, int out_size, void* d_ws, size_t ws_size,
                              hipStream_t stream) {
  const float* x      = (const float*)d_in[0];
  const float* logits = (const float*)d_in[1];
  const int*   masks  = (const int*)d_in[2];
  const float* W1     = (const float*)d_in[3];
  const float* b1     = (const float*)d_in[4];
  const float* W2     = (const float*)d_in[5];
  const float* b2     = (const float*)d_in[6];
  float* out = (float*)d_out;

  // workspace: sel (1K) | xb 8MB | w1t 16MB | w2t 16MB | H 64MB
  // part (16MB f32) aliases [xb .. first half of w1t] — dead after gemm1.
  char* ws = (char*)d_ws;
  int*   sel_e = (int*)ws;
  float* sel_g = (float*)(ws + 256);
  unsigned short* xb  = (unsigned short*)(ws + 1024);
  unsigned short* w1t = xb  + (size_t)B_SZ * L_SZ * D_SZ;
  unsigned short* w2t = w1t + (size_t)E_SZ * F_SZ * D_SZ;
  unsigned short* Hbuf = w2t + (size_t)E_SZ * D_SZ * F_SZ;
  float* part = (float*)(ws + 1024);

  prep_kernel<<<PREP_TOTAL, 256, 0, stream>>>(logits, masks, x, W1,
                                              sel_e, sel_g, xb, w1t);
  moe_gemm1<<<3072, 512, 0, stream>>>(xb, w1t, b1, sel_e, Hbuf, W2, w2t);
  moe_gemm2<<<1024, 128, 0, stream>>>(Hbuf, w2t, b2, sel_e, sel_g, part, out);
  combine_kernel<<<(B_SZ * L_SZ * D_SZ / 4) / 256, 256, 0, stream>>>(part, out);
}

// Round 6
// 239.726 us; speedup vs baseline: 1.0814x; 1.0814x over previous
//
#include <hip/hip_runtime.h>

// Problem dims
#define B_SZ 32
#define L_SZ 256
#define D_SZ 512
#define F_SZ 2048
#define E_SZ 8
#define P_SZ 64   // B_SZ * TOP_K
#define BK2  32   // LDS sub-tile K width

typedef __attribute__((ext_vector_type(8)))  short bf16x8;
typedef __attribute__((ext_vector_type(16))) float f32x16;

// counted-wait primitives (T4): NEVER vmcnt(0) in the main loop.
// CFENCE is a full compiler memory fence: required BEFORE each s_barrier
// (release: no LDS read sinks below) and AFTER each s_barrier (acquire:
// no LDS read hoists above — s_barrier is IntrNoMem to LLVM, so without
// this the next tile's ds_reads can float up past the barrier and race
// other waves' still-in-flight global_load_lds; r5 failed exactly here).
#define VMCNT(N) asm volatile("s_waitcnt vmcnt(" #N ")" ::: "memory")
#define CFENCE() asm volatile("" ::: "memory")
#define SBAR()   __builtin_amdgcn_s_barrier()

// f32 -> bf16 round-to-nearest-even (finite inputs only)
__device__ __forceinline__ unsigned short f2bf(float f) {
  unsigned int u = __builtin_bit_cast(unsigned int, f);
  u += 0x7fffu + ((u >> 16) & 1u);
  return (unsigned short)(u >> 16);
}

// async global->LDS, 16B per lane; LDS dest is wave-uniform base + lane*16
__device__ __forceinline__ void async16(const void* g, void* l) {
  __builtin_amdgcn_global_load_lds(
      (const __attribute__((address_space(1))) unsigned int*)g,
      (__attribute__((address_space(3))) unsigned int*)l, 16, 0, 0);
}

// exact gelu via A&S 7.1.26 erf (max abs err ~1.5e-7), fast hw exp/rcp
__device__ __forceinline__ float gelu_f(float x) {
  float a = fabsf(x) * 0.70710678118654752f;
  float t = __builtin_amdgcn_rcpf(1.0f + 0.3275911f * a);
  float y = t * (0.254829592f +
            t * (-0.284496736f +
            t * (1.421413741f +
            t * (-1.453152027f +
            t * 1.061405429f))));
  float e = __expf(-a * a);
  float erf_abs = 1.0f - y * e;
  float erf_v = (x < 0.f) ? -erf_abs : erf_abs;
  return 0.5f * x * (1.0f + erf_v);
}

// LDS-tile transpose+convert helper, templated on block size NT (256/512):
// in [z-block pre-offset] [R][C] f32 -> out [C][R] bf16, 64x64 tile at
// (r0, c0). tile = float[64][65] in LDS.
template <int NT>
__device__ __forceinline__ void transpose_tile(
    const float* __restrict__ ip, unsigned short* __restrict__ op,
    int R, int C, int r0, int c0, float* tile, int tid) {
  int tx = tid & 63, ty = tid >> 6;
  constexpr int RY = NT / 64;   // rows per load pass
#pragma unroll
  for (int i = 0; i < 64 / RY; ++i) {
    int r = i * RY + ty;
    tile[r * 65 + tx] = ip[(size_t)(r0 + r) * C + c0 + tx];
  }
  __syncthreads();
#pragma unroll
  for (int uu = 0; uu < 1024 / NT; ++uu) {
    int u = uu * NT + tid;
    int cc = u >> 4, q = u & 15;
    ushort4 o;
    o.x = f2bf(tile[(q * 4 + 0) * 65 + cc]);
    o.y = f2bf(tile[(q * 4 + 1) * 65 + cc]);
    o.z = f2bf(tile[(q * 4 + 2) * 65 + cc]);
    o.w = f2bf(tile[(q * 4 + 3) * 65 + cc]);
    *(ushort4*)(op + (size_t)(c0 + cc) * R + r0 + q * 4) = o;
  }
}

// ------------- prep: gates | x->bf16 | W1^T->bf16 ----------------------
#define PREP_CONV_BLKS 4096
#define PREP_TR_BLKS   2048
#define PREP_TOTAL     (1 + PREP_CONV_BLKS + PREP_TR_BLKS)

__global__ __launch_bounds__(256) void prep_kernel(
    const float* __restrict__ logits, const int* __restrict__ masks,
    const float* __restrict__ x,
    const float* __restrict__ W1,
    int* __restrict__ sel_e, float* __restrict__ sel_g,
    unsigned short* __restrict__ xb,
    unsigned short* __restrict__ w1t) {
  __shared__ float tile[64 * 65];
  int blk = blockIdx.x;
  int tid = threadIdx.x;

  if (blk == 0) {
    int b = tid;
    if (b >= B_SZ) return;
    float lg[E_SZ], p[E_SZ];
    float mx = -1e30f;
    for (int e = 0; e < E_SZ; ++e) { lg[e] = logits[b * E_SZ + e]; mx = fmaxf(mx, lg[e]); }
    float s = 0.f;
    for (int e = 0; e < E_SZ; ++e) { p[e] = expf(lg[e] - mx); s += p[e]; }
    for (int e = 0; e < E_SZ; ++e) p[e] = (masks[b * E_SZ + e] == 1) ? (p[e] / s) : 0.f;
    int i0 = 0, i1 = 1; float v0 = -1.f, v1 = -1.f;
    for (int e = 0; e < E_SZ; ++e) {
      float v = p[e];
      if (v > v0)      { v1 = v0; i1 = i0; v0 = v; i0 = e; }
      else if (v > v1) { v1 = v;  i1 = e; }
    }
    float den = v0 + v1 + 1e-9f;
    sel_e[2 * b] = i0;  sel_e[2 * b + 1] = i1;
    sel_g[2 * b] = v0 / den;
    sel_g[2 * b + 1] = v1 / den;
    return;
  }
  blk -= 1;

  if (blk < PREP_CONV_BLKS) {
    int i = blk * 256 + tid;
    float4 v = ((const float4*)x)[i];
    ushort4 o;
    o.x = f2bf(v.x); o.y = f2bf(v.y); o.z = f2bf(v.z); o.w = f2bf(v.w);
    ((ushort4*)xb)[i] = o;
    return;
  }
  blk -= PREP_CONV_BLKS;

  // W1 [E][D][F] -> w1t [E][F][D] : R=D=512, C=F=2048, 8x32 tiles (ls=5)
  int z = blk >> 8;
  int rem = blk & 255;
  int tr = rem >> 5, tc = rem & 31;
  transpose_tile<256>(W1 + (size_t)z * D_SZ * F_SZ, w1t + (size_t)z * D_SZ * F_SZ,
                      D_SZ, F_SZ, tr * 64, tc * 64, tile, tid);
}

// ------------- stage 1 + backfilled W2 transpose -----------------------
// blocks [0,1024): H[p] = gelu(X_b @ W1[e] + b1[e]) — 512 threads, block
//   tile 128(L)x256(F), 8 waves (2M x 4N) each owning 64x64 [r2 re-tile,
//   frozen]. Counted-vmcnt pipeline (T4): 2 tiles in flight, raw
//   s_barrier + acquire/release CFENCE, vmcnt(3) steady state.
// blocks [1024,3072): W2 [E][F][D] -> w2t [E][D][F] transpose backfill.
__global__ __launch_bounds__(512, 4) void moe_gemm1(
    const unsigned short* __restrict__ Xb,
    const unsigned short* __restrict__ W1t,
    const float* __restrict__ b1,
    const int* __restrict__ sel_e,
    unsigned short* __restrict__ H,
    const float* __restrict__ W2,
    unsigned short* __restrict__ w2t) {
  __shared__ __align__(16) char smem[49152];   // As 2x8KB | Bs 2x16KB
  int tid = threadIdx.x;
  int lin = blockIdx.x;

  if (lin >= 1024) {
    // W2 transpose role: R=F=2048, C=D=512, 32x8 tiles (ls=3)
    int blk = lin - 1024;
    int z = blk >> 8;
    int rem = blk & 255;
    int tr = rem >> 3, tc = rem & 7;
    transpose_tile<512>(W2 + (size_t)z * F_SZ * D_SZ, w2t + (size_t)z * F_SZ * D_SZ,
                        F_SZ, D_SZ, tr * 64, tc * 64, (float*)smem, tid);
    return;
  }

  unsigned short* As = (unsigned short*)smem;            // [2][128*32]
  unsigned short* Bs = (unsigned short*)(smem + 16384);  // [2][256*32]

  int f  = lin & 7;
  int l0 = ((lin >> 3) & 1) * 128;
  int p  = lin >> 4;
  int f0 = f * 256;
  int b  = p >> 1;
  int e  = sel_e[p];

  int lane = tid & 63;
  int w = tid >> 6;          // 0..7
  int wm = w & 1, wn = w >> 1;   // 2 x 4 wave grid over 128x256
  int m32 = lane & 31, kh = lane >> 5;
  int sw = (m32 >> 1) & 3;       // read-side XOR swizzle

  const unsigned short* Abase = Xb  + ((size_t)b * L_SZ + l0) * D_SZ;
  const unsigned short* Bbase = W1t + ((size_t)e * F_SZ + f0) * D_SZ;

  // staging: A = 512 segs of 16B (1/thread), B = 1024 segs (2/thread).
  // seg (row, slot) fetches global k-chunk slot ^ ((row>>1)&3).
  int sa   = tid;
  int rowa = sa >> 2,  ka  = ((sa  & 3) ^ ((rowa >> 1) & 3)) * 8;
  int sb1  = tid + 512;
  int rowb = sb1 >> 2, kb1 = ((sb1 & 3) ^ ((rowb >> 1) & 3)) * 8;

  const size_t aoffA  = (size_t)rowa * D_SZ + ka;    // A rows 0..127 (also B rows 0..127)
  const size_t aoffB1 = (size_t)rowb * D_SZ + kb1;   // B rows 128..255

  f32x16 acc[2][2] = {};

#define G1_STAGE(T, NB) do {                                                 \
    int kk = (T) * BK2;                                                      \
    async16(Abase + aoffA  + kk, &As[(NB) * 4096 + sa * 8]);                 \
    async16(Bbase + aoffA  + kk, &Bs[(NB) * 8192 + sa * 8]);                 \
    async16(Bbase + aoffB1 + kk, &Bs[(NB) * 8192 + sb1 * 8]);                \
  } while (0)

#define G1_COMPUTE(CB)                                                       \
  _Pragma("unroll")                                                          \
  for (int s = 0; s < 2; ++s) {                                              \
    int ko = ((((s << 1) | kh) ^ sw) << 3);                                  \
    bf16x8 a0  = *(const bf16x8*)&As[(CB) * 4096 + (wm * 64 +      m32) * BK2 + ko]; \
    bf16x8 a1  = *(const bf16x8*)&As[(CB) * 4096 + (wm * 64 + 32 + m32) * BK2 + ko]; \
    bf16x8 b0  = *(const bf16x8*)&Bs[(CB) * 8192 + (wn * 64 +      m32) * BK2 + ko]; \
    bf16x8 b1f = *(const bf16x8*)&Bs[(CB) * 8192 + (wn * 64 + 32 + m32) * BK2 + ko]; \
    acc[0][0] = __builtin_amdgcn_mfma_f32_32x32x16_bf16(a0, b0,  acc[0][0], 0, 0, 0); \
    acc[0][1] = __builtin_amdgcn_mfma_f32_32x32x16_bf16(a0, b1f, acc[0][1], 0, 0, 0); \
    acc[1][0] = __builtin_amdgcn_mfma_f32_32x32x16_bf16(a1, b0,  acc[1][0], 0, 0, 0); \
    acc[1][1] = __builtin_amdgcn_mfma_f32_32x32x16_bf16(a1, b1f, acc[1][1], 0, 0, 0); \
  }

  // prologue: tiles 0 and 1 in flight; wait for tile 0 only
  G1_STAGE(0, 0);
  G1_STAGE(1, 1);
  VMCNT(3);
  SBAR(); CFENCE();            // acquire: no ds_read hoists above

  // steady state: K = 512 = 16 sub-tiles; compute t, refill cb with t+2;
  // vmcnt(3) guarantees tile t+1 landed while t+2 stays in flight.
#pragma unroll 2
  for (int t = 0; t < 14; ++t) {
    int cb = t & 1;
    G1_COMPUTE(cb)
    CFENCE(); SBAR(); CFENCE();  // all waves done reading buf cb
    G1_STAGE(t + 2, cb);
    VMCNT(3);
    SBAR(); CFENCE();            // acquire for tile t+1 reads
  }
  G1_COMPUTE(0)                // tile 14
  VMCNT(0);                    // tile 15 landed (all 3 loads)
  SBAR(); CFENCE();
  G1_COMPUTE(1)                // tile 15
#undef G1_COMPUTE
#undef G1_STAGE

  // epilogue: +b1, gelu, bf16 direct stores (32 lanes -> 64B contiguous)
  float b1v[2];
#pragma unroll
  for (int tj = 0; tj < 2; ++tj)
    b1v[tj] = b1[e * F_SZ + f0 + wn * 64 + tj * 32 + m32];

  unsigned short* Hp = H + ((size_t)p * L_SZ + l0) * F_SZ + f0;
#pragma unroll
  for (int ti = 0; ti < 2; ++ti)
#pragma unroll
    for (int tj = 0; tj < 2; ++tj) {
      int col = wn * 64 + tj * 32 + m32;
#pragma unroll
      for (int r = 0; r < 16; ++r) {
        int row = wm * 64 + ti * 32 + (r & 3) + 8 * (r >> 2) + 4 * kh;
        Hp[(size_t)row * F_SZ + col] = f2bf(gelu_f(acc[ti][tj][r] + b1v[tj]));
      }
    }
}

// ------------- stage 2 (slot-split, full K, no atomics) ----------------
// even slot p -> part = g0*acc ; odd slot p -> Out = g1*acc + gate-wtd b2
// 128(L)x64(D) tiles, 128-thread/2-wave blocks, grid 1024 -> 4 blocks/CU
// [r3 occupancy win, frozen]. Counted-vmcnt pipeline (T4): tile t+2's 6
// loads stay in flight across both barriers and the next compute phase.
__global__ __launch_bounds__(128, 2) void moe_gemm2(
    const unsigned short* __restrict__ H,
    const unsigned short* __restrict__ W2t,
    const float* __restrict__ b2,
    const int* __restrict__ sel_e,
    const float* __restrict__ sel_g,
    float* __restrict__ part,
    float* __restrict__ Out) {
  __shared__ __align__(16) unsigned short As[2][128 * BK2];  // 16 KB
  __shared__ __align__(16) unsigned short Bs[2][64 * BK2];   //  8 KB

  int lin = blockIdx.x;
  int q   = lin & 7;             // XCD
  int d   = (lin >> 3) & 7;      // 8 d-tiles of 64 — same XCD across d
  int g8  = lin >> 6;
  int gg  = g8 * 8 + q;          // (p, l-tile), 0..127
  int p   = gg >> 1;
  int l0  = (gg & 1) * 128;
  int d0  = d * 64;
  int b   = p >> 1;
  int e   = sel_e[p];
  float g = sel_g[p];

  int tid = threadIdx.x;         // 0..127
  int lane = tid & 63;
  int wm = tid >> 6;             // 2 waves = M split; wn == 0
  int m32 = lane & 31, kh = lane >> 5;
  int sw = (m32 >> 1) & 3;

  const unsigned short* Abase = H   + ((size_t)p * L_SZ + l0) * F_SZ;
  const unsigned short* Bbase = W2t + ((size_t)e * D_SZ + d0) * F_SZ;

  // staging: A = 512 segs of 16B (4/thread), B = 256 segs (2/thread).
  // seg (row, slot) fetches global k-chunk slot ^ ((row>>1)&3).
  int    saA[4]; size_t aoffA[4];
#pragma unroll
  for (int j = 0; j < 4; ++j) {
    int s = tid + j * 128;
    int row = s >> 2, ks = ((s & 3) ^ ((row >> 1) & 3)) * 8;
    saA[j] = s; aoffA[j] = (size_t)row * F_SZ + ks;
  }
  int    saB[2]; size_t aoffB[2];
#pragma unroll
  for (int j = 0; j < 2; ++j) {
    int s = tid + j * 128;
    int row = s >> 2, ks = ((s & 3) ^ ((row >> 1) & 3)) * 8;
    saB[j] = s; aoffB[j] = (size_t)row * F_SZ + ks;
  }

  f32x16 acc[2][2] = {};

#define G2_STAGE(T, NB) do {                                                 \
    int kk = (T) * BK2;                                                      \
    _Pragma("unroll")                                                        \
    for (int j = 0; j < 4; ++j)                                              \
      async16(Abase + aoffA[j] + kk, &As[NB][saA[j] * 8]);                   \
    _Pragma("unroll")                                                        \
    for (int j = 0; j < 2; ++j)                                              \
      async16(Bbase + aoffB[j] + kk, &Bs[NB][saB[j] * 8]);                   \
  } while (0)

#define G2_COMPUTE(CB)                                                       \
  _Pragma("unroll")                                                          \
  for (int s = 0; s < 2; ++s) {     /* K=16 substep */                       \
    int ko = (((s << 1) | kh) ^ sw) << 3;                                    \
    bf16x8 a0  = *(const bf16x8*)&As[CB][(wm * 64 +      m32) * BK2 + ko];   \
    bf16x8 a1  = *(const bf16x8*)&As[CB][(wm * 64 + 32 + m32) * BK2 + ko];   \
    bf16x8 b0  = *(const bf16x8*)&Bs[CB][(          m32) * BK2 + ko];        \
    bf16x8 b1f = *(const bf16x8*)&Bs[CB][(     32 + m32) * BK2 + ko];        \
    acc[0][0] = __builtin_amdgcn_mfma_f32_32x32x16_bf16(a0, b0,  acc[0][0], 0, 0, 0); \
    acc[0][1] = __builtin_amdgcn_mfma_f32_32x32x16_bf16(a0, b1f, acc[0][1], 0, 0, 0); \
    acc[1][0] = __builtin_amdgcn_mfma_f32_32x32x16_bf16(a1, b0,  acc[1][0], 0, 0, 0); \
    acc[1][1] = __builtin_amdgcn_mfma_f32_32x32x16_bf16(a1, b1f, acc[1][1], 0, 0, 0); \
  }

  // prologue: tiles 0 and 1 in flight; wait for tile 0 only
  G2_STAGE(0, 0);
  G2_STAGE(1, 1);
  VMCNT(6);
  SBAR(); CFENCE();            // acquire: no ds_read hoists above

  // steady state: K = 2048 = 64 sub-tiles; compute t, refill cb with t+2;
  // vmcnt(6) guarantees tile t+1 landed while t+2 stays in flight.
#pragma unroll 2
  for (int t = 0; t < 62; ++t) {
    int cb = t & 1;
    G2_COMPUTE(cb)
    CFENCE(); SBAR(); CFENCE();  // all waves done reading buf cb
    G2_STAGE(t + 2, cb);
    VMCNT(6);
    SBAR(); CFENCE();            // acquire for tile t+1 reads
  }
  G2_COMPUTE(0)                // tile 62
  VMCNT(0);                    // tile 63 landed
  SBAR(); CFENCE();
  G2_COMPUTE(1)                // tile 63
#undef G2_COMPUTE
#undef G2_STAGE

  // epilogue: gate-scale (+ gate-weighted b2 on odd slot), direct f32 stores
  float bias[2] = {0.f, 0.f};
  if (p & 1) {
    int e0 = sel_e[2 * b], e1 = sel_e[2 * b + 1];
    float g0 = sel_g[2 * b], g1 = sel_g[2 * b + 1];
#pragma unroll
    for (int tj = 0; tj < 2; ++tj) {
      int dd = d0 + tj * 32 + m32;
      bias[tj] = g0 * b2[e0 * D_SZ + dd] + g1 * b2[e1 * D_SZ + dd];
    }
  }
  float* dst = (p & 1) ? Out : part;
  float* Op = dst + ((size_t)b * L_SZ + l0) * D_SZ + d0;
#pragma unroll
  for (int ti = 0; ti < 2; ++ti)
#pragma unroll
    for (int tj = 0; tj < 2; ++tj) {
      int col = tj * 32 + m32;
#pragma unroll
      for (int r = 0; r < 16; ++r) {
        int row = wm * 64 + ti * 32 + (r & 3) + 8 * (r >> 2) + 4 * kh;
        Op[(size_t)row * D_SZ + col] = g * acc[ti][tj][r] + bias[tj];
      }
    }
}

// ------------- combine: Out += part ------------------------------------
__global__ __launch_bounds__(256) void combine_kernel(
    const float* __restrict__ part, float* __restrict__ Out) {
  int i = blockIdx.x * 256 + threadIdx.x;
  float4 pv = ((const float4*)part)[i];
  float4 o  = ((float4*)Out)[i];
  o.x += pv.x; o.y += pv.y; o.z += pv.z; o.w += pv.w;
  ((float4*)Out)[i] = o;
}

extern "C" void kernel_launch(void* const* d_in, const int* in_sizes, int n_in,
                              void* d_out, int out_size, void* d_ws, size_t ws_size,
                              hipStream_t stream) {
  const float* x      = (const float*)d_in[0];
  const float* logits = (const float*)d_in[1];
  const int*   masks  = (const int*)d_in[2];
  const float* W1     = (const float*)d_in[3];
  const float* b1     = (const float*)d_in[4];
  const float* W2     = (const float*)d_in[5];
  const float* b2     = (const float*)d_in[6];
  float* out = (float*)d_out;

  // workspace: sel (1K) | xb 8MB | w1t 16MB | w2t 16MB | H 64MB
  // part (16MB f32) aliases [xb .. first half of w1t] — dead after gemm1.
  char* ws = (char*)d_ws;
  int*   sel_e = (int*)ws;
  float* sel_g = (float*)(ws + 256);
  unsigned short* xb  = (unsigned short*)(ws + 1024);
  unsigned short* w1t = xb  + (size_t)B_SZ * L_SZ * D_SZ;
  unsigned short* w2t = w1t + (size_t)E_SZ * F_SZ * D_SZ;
  unsigned short* Hbuf = w2t + (size_t)E_SZ * D_SZ * F_SZ;
  float* part = (float*)(ws + 1024);

  prep_kernel<<<PREP_TOTAL, 256, 0, stream>>>(logits, masks, x, W1,
                                              sel_e, sel_g, xb, w1t);
  moe_gemm1<<<3072, 512, 0, stream>>>(xb, w1t, b1, sel_e, Hbuf, W2, w2t);
  moe_gemm2<<<1024, 128, 0, stream>>>(Hbuf, w2t, b2, sel_e, sel_g, part, out);
  combine_kernel<<<(B_SZ * L_SZ * D_SZ / 4) / 256, 256, 0, stream>>>(part, out);
}